// Round 14
// baseline (326.445 us; speedup 1.0000x reference)
//
#include <hip/hip_runtime.h>
#include <hip/hip_fp16.h>
#include <math.h>

#define N_NODES 100000
#define EMB 64
#define N_EDGES 1200000
#define N_ELEM (N_NODES * EMB)   // 6,400,000
#define SCAN_CHUNK 1024
#define SCAN_NBLK ((N_NODES + SCAN_CHUNK - 1) / SCAN_CHUNK)   // 98
#define NPART 8
#define PART_SIZE (N_NODES / NPART)    // 12,500 exact
#define SC_GRID 2048
#define SC_TPB 256

// ---------------------------------------------------------------------------
// Threefry-2x32, 20 rounds — JAX partitionable mode (verified R6-R13)
// ---------------------------------------------------------------------------
__device__ __forceinline__ unsigned rotl32(unsigned v, int r) {
    return (v << r) | (v >> (32 - r));
}

__device__ __forceinline__ void threefry2x32(unsigned k0, unsigned k1,
                                             unsigned c0, unsigned c1,
                                             unsigned& o0, unsigned& o1) {
    const unsigned ks0 = k0;
    const unsigned ks1 = k1;
    const unsigned ks2 = k0 ^ k1 ^ 0x1BD11BDAu;
    unsigned x0 = c0 + ks0;
    unsigned x1 = c1 + ks1;
#define TF_RND(r) { x0 += x1; x1 = rotl32(x1, r); x1 ^= x0; }
    TF_RND(13) TF_RND(15) TF_RND(26) TF_RND(6)
    x0 += ks1; x1 += ks2 + 1u;
    TF_RND(17) TF_RND(29) TF_RND(16) TF_RND(24)
    x0 += ks2; x1 += ks0 + 2u;
    TF_RND(13) TF_RND(15) TF_RND(26) TF_RND(6)
    x0 += ks0; x1 += ks1 + 3u;
    TF_RND(17) TF_RND(29) TF_RND(16) TF_RND(24)
    x0 += ks1; x1 += ks2 + 4u;
    TF_RND(13) TF_RND(15) TF_RND(26) TF_RND(6)
    x0 += ks2; x1 += ks0 + 5u;
#undef TF_RND
    o0 = x0;
    o1 = x1;
}

__device__ __forceinline__ bool drop_keep(unsigned i) {
    unsigned o0, o1;
    threefry2x32(0u, 42u, 0u, i, o0, o1);
    unsigned bits = o0 ^ o1;
    float u = __uint_as_float((bits >> 9) | 0x3f800000u) - 1.0f;
    return u < 0.9f;
}

// ---------------------------------------------------------------------------
// CSR construction (hist + 3-pass scan verified R9-R13)
// ---------------------------------------------------------------------------
__global__ void k_hist(const int* __restrict__ dst, int* __restrict__ cnt) {
    int e = blockIdx.x * blockDim.x + threadIdx.x;
    if (e < N_EDGES) atomicAdd(&cnt[dst[e]], 1);
}

__global__ void k_scan1(const int* __restrict__ cnt, int* __restrict__ local,
                        int* __restrict__ bsum, float* __restrict__ dis) {
    __shared__ int wsum[16];
    const int tid = threadIdx.x;
    const int lane = tid & 63;
    const int wid = tid >> 6;
    int i = blockIdx.x * SCAN_CHUNK + tid;
    int v = (i < N_NODES) ? cnt[i] : 0;
    if (i < N_NODES) dis[i] = (v > 0) ? rsqrtf((float)v) : 0.0f;
    int x = v;
#pragma unroll
    for (int off = 1; off < 64; off <<= 1) {
        int t = __shfl_up(x, off, 64);
        if (lane >= off) x += t;
    }
    if (lane == 63) wsum[wid] = x;
    __syncthreads();
    if (wid == 0 && lane < 16) {
        int w = wsum[lane];
#pragma unroll
        for (int off = 1; off < 16; off <<= 1) {
            int t = __shfl_up(w, off, 64);
            if (lane >= off) w += t;
        }
        wsum[lane] = w;
    }
    __syncthreads();
    int wexc = (wid == 0) ? 0 : wsum[wid - 1];
    if (i < N_NODES) local[i] = (x + wexc) - v;
    if (tid == 0) bsum[blockIdx.x] = wsum[15];
}

__global__ void k_scan2(const int* __restrict__ bsum, int* __restrict__ bofs) {
    __shared__ int sh[128];
    int t = threadIdx.x;
    int v = (t < SCAN_NBLK) ? bsum[t] : 0;
    sh[t] = v;
    __syncthreads();
    for (int off = 1; off < 128; off <<= 1) {
        int add = (t >= off) ? sh[t - off] : 0;
        __syncthreads();
        sh[t] += add;
        __syncthreads();
    }
    if (t < SCAN_NBLK) bofs[t] = sh[t] - v;
}

__global__ void k_scan3(int* __restrict__ cursor_local, const int* __restrict__ bofs,
                        int* __restrict__ rowptr) {
    int i = blockIdx.x * SCAN_CHUNK + threadIdx.x;
    if (i < N_NODES) {
        int r = cursor_local[i] + bofs[blockIdx.x];
        rowptr[i] = r;
        cursor_local[i] = r;
    }
    if (i == 0) rowptr[N_NODES] = N_EDGES;
}

// z0 = fp16(dis[node] * emb); 8 elems/thread
__global__ void k_cvt(const float* __restrict__ emb, const float* __restrict__ dis,
                      __half* __restrict__ z0) {
    int base = (blockIdx.x * blockDim.x + threadIdx.x) * 8;
    if (base >= N_ELEM) return;
    float d = dis[base >> 6];
    const float4 f0 = *reinterpret_cast<const float4*>(emb + base);
    const float4 f1 = *reinterpret_cast<const float4*>(emb + base + 4);
    __half2 h0 = __float22half2_rn(make_float2(f0.x * d, f0.y * d));
    __half2 h1 = __float22half2_rn(make_float2(f0.z * d, f0.w * d));
    __half2 h2 = __float22half2_rn(make_float2(f1.x * d, f1.y * d));
    __half2 h3 = __float22half2_rn(make_float2(f1.z * d, f1.w * d));
    uint4 u;
    u.x = *(unsigned*)&h0; u.y = *(unsigned*)&h1;
    u.z = *(unsigned*)&h2; u.w = *(unsigned*)&h3;
    *reinterpret_cast<uint4*>(z0 + base) = u;
}

// dst-range partitioned scatter v2: 4 edges/thread/iter via int4 loads of
// dst+src (4x MLP on the read->atomic chain). Record = 4B src only.
__global__ void k_scatter(const int* __restrict__ src, const int* __restrict__ dst,
                          int* __restrict__ cursor, int* __restrict__ edges) {
    const int p = blockIdx.x & (NPART - 1);
    const int lo = p * PART_SIZE;
    const int hi = lo + PART_SIZE;
    const int stride = (SC_GRID / NPART) * SC_TPB * 4;
    int e = (((blockIdx.x >> 3) * SC_TPB) + threadIdx.x) * 4;
    for (; e < N_EDGES; e += stride) {
        const int4 d4 = *reinterpret_cast<const int4*>(dst + e);
        const int4 s4 = *reinterpret_cast<const int4*>(src + e);
        if (d4.x >= lo && d4.x < hi) edges[atomicAdd(&cursor[d4.x], 1)] = s4.x;
        if (d4.y >= lo && d4.y < hi) edges[atomicAdd(&cursor[d4.y], 1)] = s4.y;
        if (d4.z >= lo && d4.z < hi) edges[atomicAdd(&cursor[d4.z], 1)] = s4.z;
        if (d4.w >= lo && d4.w < hi) edges[atomicAdd(&cursor[d4.w], 1)] = s4.w;
    }
}

// ---------------------------------------------------------------------------
// Propagation v5: z-table formulation. 4 nodes/wave (16-lane groups); lane
// holds 4 dims as fp16 (8B gather per row); pure adds (no per-edge norm);
// x8 edge unroll -> up to 32 outstanding gathers/wave.
// G = sum z[s];  out = dis[n]*G;  z_next = dis[n]^2*G (fp16)
// MODE 0: z_next write; acc = emb_own + out
// MODE 1: z_next write; acc += out
// MODE 2: acc = dropout((acc + out)/4)   [no z write]
// ---------------------------------------------------------------------------
__device__ __forceinline__ float4 h4_to_f4(uint2 u) {
    __half2 p = *(__half2*)&u.x, q = *(__half2*)&u.y;
    float2 a = __half22float2(p), b = __half22float2(q);
    return make_float4(a.x, a.y, b.x, b.y);
}

template <int MODE>
__global__ void k_agg(const int* __restrict__ rowptr, const int* __restrict__ edges,
                      const float* __restrict__ dis,
                      const __half* __restrict__ z, __half* __restrict__ znext,
                      const float* __restrict__ own, float* __restrict__ acc) {
    const int gwid = (blockIdx.x * blockDim.x + threadIdx.x) >> 6;
    const int lane = threadIdx.x & 63;
    const int g = lane >> 4;           // group = node offset within wave
    const int l16 = lane & 15;         // dims 4*l16 .. 4*l16+3
    const int n = (gwid << 2) + g;
    if (n >= N_NODES) return;
    const int begin = rowptr[n];
    const int end = rowptr[n + 1];
    const __half* zb = z + (l16 << 2);
    float4 s = make_float4(0.f, 0.f, 0.f, 0.f);
    int j = begin;
    for (; j + 7 < end; j += 8) {
        int e0 = edges[j],     e1 = edges[j + 1], e2 = edges[j + 2], e3 = edges[j + 3];
        int e4 = edges[j + 4], e5 = edges[j + 5], e6 = edges[j + 6], e7 = edges[j + 7];
        float4 v0 = h4_to_f4(*reinterpret_cast<const uint2*>(zb + (size_t)e0 * EMB));
        float4 v1 = h4_to_f4(*reinterpret_cast<const uint2*>(zb + (size_t)e1 * EMB));
        float4 v2 = h4_to_f4(*reinterpret_cast<const uint2*>(zb + (size_t)e2 * EMB));
        float4 v3 = h4_to_f4(*reinterpret_cast<const uint2*>(zb + (size_t)e3 * EMB));
        float4 v4 = h4_to_f4(*reinterpret_cast<const uint2*>(zb + (size_t)e4 * EMB));
        float4 v5 = h4_to_f4(*reinterpret_cast<const uint2*>(zb + (size_t)e5 * EMB));
        float4 v6 = h4_to_f4(*reinterpret_cast<const uint2*>(zb + (size_t)e6 * EMB));
        float4 v7 = h4_to_f4(*reinterpret_cast<const uint2*>(zb + (size_t)e7 * EMB));
        s.x += ((v0.x + v1.x) + (v2.x + v3.x)) + ((v4.x + v5.x) + (v6.x + v7.x));
        s.y += ((v0.y + v1.y) + (v2.y + v3.y)) + ((v4.y + v5.y) + (v6.y + v7.y));
        s.z += ((v0.z + v1.z) + (v2.z + v3.z)) + ((v4.z + v5.z) + (v6.z + v7.z));
        s.w += ((v0.w + v1.w) + (v2.w + v3.w)) + ((v4.w + v5.w) + (v6.w + v7.w));
    }
    for (; j + 3 < end; j += 4) {
        int e0 = edges[j], e1 = edges[j + 1], e2 = edges[j + 2], e3 = edges[j + 3];
        float4 v0 = h4_to_f4(*reinterpret_cast<const uint2*>(zb + (size_t)e0 * EMB));
        float4 v1 = h4_to_f4(*reinterpret_cast<const uint2*>(zb + (size_t)e1 * EMB));
        float4 v2 = h4_to_f4(*reinterpret_cast<const uint2*>(zb + (size_t)e2 * EMB));
        float4 v3 = h4_to_f4(*reinterpret_cast<const uint2*>(zb + (size_t)e3 * EMB));
        s.x += (v0.x + v1.x) + (v2.x + v3.x);
        s.y += (v0.y + v1.y) + (v2.y + v3.y);
        s.z += (v0.z + v1.z) + (v2.z + v3.z);
        s.w += (v0.w + v1.w) + (v2.w + v3.w);
    }
    for (; j < end; ++j) {
        float4 v0 = h4_to_f4(*reinterpret_cast<const uint2*>(zb + (size_t)edges[j] * EMB));
        s.x += v0.x; s.y += v0.y; s.z += v0.z; s.w += v0.w;
    }
    const float dn = dis[n];
    const float4 out = make_float4(s.x * dn, s.y * dn, s.z * dn, s.w * dn);
    const size_t ridx = (size_t)n * EMB + (l16 << 2);
    if (MODE == 0 || MODE == 1) {
        const float dn2 = dn * dn;
        __half2 h0 = __float22half2_rn(make_float2(s.x * dn2, s.y * dn2));
        __half2 h1 = __float22half2_rn(make_float2(s.z * dn2, s.w * dn2));
        uint2 u;
        u.x = *(unsigned*)&h0; u.y = *(unsigned*)&h1;
        *reinterpret_cast<uint2*>(znext + ridx) = u;
        if (MODE == 0) {
            float4 o = *reinterpret_cast<const float4*>(own + ridx);
            *reinterpret_cast<float4*>(acc + ridx) =
                make_float4(o.x + out.x, o.y + out.y, o.z + out.z, o.w + out.w);
        } else {
            float4 a = *reinterpret_cast<const float4*>(acc + ridx);
            *reinterpret_cast<float4*>(acc + ridx) =
                make_float4(a.x + out.x, a.y + out.y, a.z + out.z, a.w + out.w);
        }
    } else {
        float4 a = *reinterpret_cast<const float4*>(acc + ridx);
        float4 t = make_float4(a.x + out.x, a.y + out.y, a.z + out.z, a.w + out.w);
        const float sc = 0.25f / 0.9f;
        unsigned base = (unsigned)ridx;
        float4 o;
        o.x = drop_keep(base + 0u) ? t.x * sc : 0.f;
        o.y = drop_keep(base + 1u) ? t.y * sc : 0.f;
        o.z = drop_keep(base + 2u) ? t.z * sc : 0.f;
        o.w = drop_keep(base + 3u) ? t.w * sc : 0.f;
        *reinterpret_cast<float4*>(acc + ridx) = o;
    }
}

// ---------------------------------------------------------------------------
// Launch (split path; cooperative fusion measured 3.2x slower in R11)
// ---------------------------------------------------------------------------
extern "C" void kernel_launch(void* const* d_in, const int* in_sizes, int n_in,
                              void* d_out, int out_size, void* d_ws, size_t ws_size,
                              hipStream_t stream) {
    const float* emb = (const float*)d_in[0];
    const int* eidx = (const int*)d_in[1];
    const int* src = eidx;             // edge_index[0]
    const int* dst = eidx + N_EDGES;   // edge_index[1]
    float* acc = (float*)d_out;

    // workspace layout (bytes)
    char* ws = (char*)d_ws;
    int*    cnt     = (int*)(ws + 0);           // 100,000 ints
    int*    cursor  = (int*)(ws + 400000);      // 100,000 ints (scan `local` alias)
    int*    bsum    = (int*)(ws + 800000);      // 98
    int*    bofs    = (int*)(ws + 800400);      // 98
    int*    rowptr  = (int*)(ws + 800800);      // 100,001
    float*  dis     = (float*)(ws + 1200808);   // 100,000
    int*    edges   = (int*)(ws + 1600808);     // 1,200,000 ints (4B records)
    __half* z0      = (__half*)(ws + 6400816);  // 6.4M halves (16B-aligned)
    __half* z1      = (__half*)(ws + 19200816); // 6.4M halves
    __half* z2      = (__half*)(ws + 32000816); // 6.4M halves; end ~44.8 MB

    const int BLK = 256;
    const int gE   = (N_EDGES + BLK - 1) / BLK;
    const int gCvt = (N_ELEM / 8 + BLK - 1) / BLK;
    const int gAgg = ((N_NODES + 3) / 4 * 64 + BLK - 1) / BLK;   // 4 nodes/wave

    // CSR build + scaled fp16 table
    hipMemsetAsync(cnt, 0, N_NODES * sizeof(int), stream);
    k_hist<<<gE, BLK, 0, stream>>>(dst, cnt);
    k_scan1<<<SCAN_NBLK, SCAN_CHUNK, 0, stream>>>(cnt, cursor, bsum, dis);
    k_scan2<<<1, 128, 0, stream>>>(bsum, bofs);
    k_scan3<<<SCAN_NBLK, SCAN_CHUNK, 0, stream>>>(cursor, bofs, rowptr);
    k_cvt<<<gCvt, BLK, 0, stream>>>(emb, dis, z0);
    k_scatter<<<SC_GRID, SC_TPB, 0, stream>>>(src, dst, cursor, edges);

    // 3 propagation layers (z-table gathers; acc + final dropout fused)
    k_agg<0><<<gAgg, BLK, 0, stream>>>(rowptr, edges, dis, z0, z1, emb, acc);
    k_agg<1><<<gAgg, BLK, 0, stream>>>(rowptr, edges, dis, z1, z2, nullptr, acc);
    k_agg<2><<<gAgg, BLK, 0, stream>>>(rowptr, edges, dis, z2, nullptr, nullptr, acc);
}